// Round 8
// baseline (424.411 us; speedup 1.0000x reference)
//
#include <hip/hip_runtime.h>

#define DEVI __device__ __forceinline__

typedef __bf16 bf16_t;
typedef __bf16 bf16x8 __attribute__((ext_vector_type(8)));
typedef __bf16 bf16x4v __attribute__((ext_vector_type(4)));
typedef float f32x4 __attribute__((ext_vector_type(4)));

// scale * log2(e), folded into the Q projection epilogue
#define CSL 0.18033688011112042f

// raw v_exp_f32: scores are bounded (|z| ~ 10), so the OCML denormal-fixup
// sequence (~5 extra VALU ops per exp) is pure overhead.
#if __has_builtin(__builtin_amdgcn_exp2f)
DEVI float fast_exp2(float x) { return __builtin_amdgcn_exp2f(x); }
#else
DEVI float fast_exp2(float x) {
  float r;
  asm volatile("v_exp_f32 %0, %1\n\ts_nop 1" : "=v"(r) : "v"(x));
  return r;
}
#endif

// ---- async 16B global -> LDS (dest = wave-uniform base + lane*16) ----
DEVI void async16(void* lds, const void* g) {
  __builtin_amdgcn_global_load_lds(
      (const __attribute__((address_space(1))) unsigned int*)g,
      (__attribute__((address_space(3))) unsigned int*)lds, 16, 0, 0);
}

// ---- fp32 -> bf16 conversions, fused over multiple tensors ----
__global__ __launch_bounds__(256) void cvt3(const float* __restrict__ a,
                                            const float* __restrict__ b,
                                            const float* __restrict__ c,
                                            bf16_t* __restrict__ da,
                                            bf16_t* __restrict__ db,
                                            bf16_t* __restrict__ dc, int n) {
  const float* s = (blockIdx.y == 0) ? a : (blockIdx.y == 1) ? b : c;
  bf16_t* d = (blockIdx.y == 0) ? da : (blockIdx.y == 1) ? db : dc;
  const int i = (blockIdx.x * 256 + threadIdx.x) * 4;
  if (i < n) {
    const float4 f = *(const float4*)(s + i);
    bf16x4v o;
    o.x = (bf16_t)f.x; o.y = (bf16_t)f.y; o.z = (bf16_t)f.z; o.w = (bf16_t)f.w;
    *(bf16x4v*)(d + i) = o;
  }
}
// 4 weight tensors in one launch; y=0,1 are the big ones (na), y=2,3 small (nc)
__global__ __launch_bounds__(256) void cvt4(const float* __restrict__ a,
                                            const float* __restrict__ b,
                                            const float* __restrict__ c,
                                            const float* __restrict__ d,
                                            bf16_t* __restrict__ da,
                                            bf16_t* __restrict__ db,
                                            bf16_t* __restrict__ dc,
                                            bf16_t* __restrict__ dd,
                                            int na, int nc) {
  const int y = blockIdx.y;
  const float* s = (y == 0) ? a : (y == 1) ? b : (y == 2) ? c : d;
  bf16_t* dst = (y == 0) ? da : (y == 1) ? db : (y == 2) ? dc : dd;
  const int n = (y < 2) ? na : nc;
  const int i = (blockIdx.x * 256 + threadIdx.x) * 4;
  if (i < n) {
    const float4 f = *(const float4*)(s + i);
    bf16x4v o;
    o.x = (bf16_t)f.x; o.y = (bf16_t)f.y; o.z = (bf16_t)f.z; o.w = (bf16_t)f.w;
    *(bf16x4v*)(dst + i) = o;
  }
}

// ===================== GEMM: out = A @ W^T (+bias) =====================
// MODE 0: bf16 out row-major. MODE 1: fp32 out + fp32 bias. MODE 2: bf16
// transposed store (B,G*D,T). MODE 3: bf16 out scaled by CSL (Q projection).
// BM x BN block tile, 4 waves, each owning (BM/2)x(BN/2).
//
// BK=64: halves the barrier count vs BK=32 (the 2-barrier drain per step
// was the exposed cost at 2-3 blocks/CU), 32 MFMA per barrier-pair, same
// staging instruction count per unit K. LDS = (BM+BN)*64*2 = 32 KB at 128^2
// (still 4 blocks/CU; m132's BK=128 failure was the 64 KB cliff).
//
// Row stride is now 128 B -> classic 32-way read conflict; fixed with the
// attn-proven pair: PRE-SWIZZLED global source for global_load_lds (m173;
// source chunk = (t&7)^(srow&7), LDS dest linear) + XOR on fragment reads
// (chunk (kc*4+quad)^(l15&7)). Residual aliasing is 2 lanes/bank = free.
// K-reduction order is unchanged -> bitwise-identical results.
template<int MODE, int BM, int BN>
DEVI void gemm_core(const bf16_t* __restrict__ A, const bf16_t* __restrict__ W,
                    const float* __restrict__ bias, void* __restrict__ outv,
                    int N, int K, int bx, int by)
{
  __shared__ __align__(16) bf16_t Al[BM * 64];
  __shared__ __align__(16) bf16_t Bl[BN * 64];
  constexpr int MT = BM / 32, NT = BN / 32;   // 16x16 frags per wave
  const int t = threadIdx.x;
  const int w = t >> 6, lane = t & 63;
  const int l15 = lane & 15, quad = lane >> 4;
  const int wm = (w >> 1) * (BM / 2), wn = (w & 1) * (BN / 2);
  const int m0 = by * BM, n0 = bx * BN;
  const int srow = t >> 3;                    // staging row 0..31 (w*8 + lane>>3)
  const int ssw = ((t & 7) ^ (srow & 7)) * 8; // pre-swizzled source elem offset
  const int xg = l15 & 7;                     // XOR key for fragment reads

  f32x4 acc[MT][NT] = {};

  for (int kk = 0; kk < K; kk += 64) {
    __syncthreads();
#pragma unroll
    for (int i = 0; i < BM / 32; ++i)
      async16(Al + i * 2048 + w * 512,
              A + (size_t)(m0 + i * 32 + srow) * K + kk + ssw);
#pragma unroll
    for (int i = 0; i < BN / 32; ++i)
      async16(Bl + i * 2048 + w * 512,
              W + (size_t)(n0 + i * 32 + srow) * K + kk + ssw);
    __syncthreads();
#pragma unroll
    for (int kc = 0; kc < 2; ++kc) {
      bf16x8 af[MT], bfr[NT];
#pragma unroll
      for (int x = 0; x < MT; ++x)
        af[x]  = *(const bf16x8*)&Al[(wm + x * 16 + l15) * 64 + (((kc * 4 + quad) ^ xg) << 3)];
#pragma unroll
      for (int x = 0; x < NT; ++x)
        bfr[x] = *(const bf16x8*)&Bl[(wn + x * 16 + l15) * 64 + (((kc * 4 + quad) ^ xg) << 3)];
#pragma unroll
      for (int mt = 0; mt < MT; ++mt)
#pragma unroll
        for (int nt = 0; nt < NT; ++nt)
          acc[mt][nt] = __builtin_amdgcn_mfma_f32_16x16x32_bf16(af[mt], bfr[nt], acc[mt][nt], 0, 0, 0);
    }
  }

#pragma unroll
  for (int mt = 0; mt < MT; ++mt) {
#pragma unroll
    for (int nt = 0; nt < NT; ++nt) {
      const int n = n0 + wn + nt * 16 + l15;
#pragma unroll
      for (int r = 0; r < 4; ++r) {
        const int m = m0 + wm + mt * 16 + quad * 4 + r;   // C-layout row
        const float v = acc[mt][nt][r];
        if (MODE == 0) {
          ((bf16_t*)outv)[(size_t)m * N + n] = (bf16_t)v;
        } else if (MODE == 1) {
          ((float*)outv)[(size_t)m * N + n] = v + bias[n];
        } else if (MODE == 2) {
          ((bf16_t*)outv)[(size_t)(m >> 11) * (512 * 2048) + (size_t)n * 2048 + (m & 2047)] = (bf16_t)v;
        } else {
          ((bf16_t*)outv)[(size_t)m * N + n] = (bf16_t)(v * CSL);
        }
      }
    }
  }
}

// ---- merged Q/K/V projection: ONE 768-block launch, 3 blocks/CU ----
// blocks [0,512): Q proj (4096x2048, 128^2 tiles, CSL-scaled)
// blocks [512,640): K proj (4096x512, 128^2 tiles)
// blocks [640,768): V proj (4096x512, 128^2 tiles, transposed store)
__global__ __launch_bounds__(256) void gemm_qkv(
    const bf16_t* __restrict__ qb, const bf16_t* __restrict__ Wqb, bf16_t* __restrict__ Qp,
    const bf16_t* __restrict__ kb, const bf16_t* __restrict__ Wkb, bf16_t* __restrict__ kp,
    const bf16_t* __restrict__ vb, const bf16_t* __restrict__ Wvb, bf16_t* __restrict__ vt)
{
  const int bid = blockIdx.x;
  if (bid < 512) {
    gemm_core<3, 128, 128>(qb, Wqb, nullptr, Qp, 2048, 2048, bid & 15, bid >> 4);
  } else if (bid < 640) {
    const int r = bid - 512;
    gemm_core<0, 128, 128>(kb, Wkb, nullptr, kp, 512, 2048, r & 3, r >> 2);
  } else {
    const int r = bid - 640;
    gemm_core<2, 128, 128>(vb, Wvb, nullptr, vt, 512, 2048, r & 3, r >> 2);
  }
}

// Output projection: 128x128 tile
__global__ __launch_bounds__(256) void gemm_bias_f32(const bf16_t* __restrict__ A,
                                                     const bf16_t* __restrict__ W,
                                                     const float* __restrict__ bias,
                                                     float* __restrict__ out, int N, int K) {
  gemm_core<1, 128, 128>(A, W, bias, out, N, K, blockIdx.x, blockIdx.y);
}

// ===================== Flash attention (no-max softmax, S^T orientation) ==
// EXACT R1 kernel (measured 106-108 us, VGPR 64, occ 34%): all later attn
// variants (odd-key P swizzle, gload_lds staging, early-issue, setprio)
// raised VGPR past the 64-reg occupancy boundary and regressed. The 7.3e6
// 2-way P-write conflict is hidden under wave overlap at this occupancy.
__global__ __launch_bounds__(256) void attn_kernel(
    const bf16_t* __restrict__ Qp, const bf16_t* __restrict__ Kp,
    const bf16_t* __restrict__ Vt, bf16_t* __restrict__ O)
{
  __shared__ __align__(16) bf16_t Kl[64 * 64];         // [s][d], swizzled
  __shared__ __align__(16) bf16_t Vl[64 * 64];         // [d][s], swizzled
  __shared__ __align__(16) bf16_t Pl[4 * 32 * 64];     // per-wave [q][s], swizzled

  const int t = threadIdx.x;
  const int w = t >> 6, lane = t & 63;
  const int l15 = lane & 15, quad = lane >> 4;
  const int h = blockIdx.y, b = blockIdx.z, g = h & 7;
  const int t0 = blockIdx.x * 128 + w * 32;

  const size_t qbase = (size_t)b * (2048u * 2048u) + (size_t)h * 64;
  const size_t kbase = (size_t)b * (2048u * 512u) + (size_t)g * 64;
  const size_t vbase = (size_t)b * (512u * 2048u) + (size_t)(g * 64) * 2048u;

  // Q fragments (B-layout: l15 = q-row, k = quad*8+j); [qtile][kchunk]
  bf16x8 qf[2][2];
#pragma unroll
  for (int nt = 0; nt < 2; ++nt)
#pragma unroll
    for (int kc = 0; kc < 2; ++kc)
      qf[nt][kc] = *(const bf16x8*)&Qp[qbase + (size_t)(t0 + nt * 16 + l15) * 2048 + kc * 32 + quad * 8];

  f32x4 oacc[2][4] = {};
  float rs[2] = {0.f, 0.f};     // per-lane partial softmax denominators

  const int xp = (l15 & 7) << 1;           // XOR key for P chunks (8B)
  const int xk = l15 & 7;                  // XOR key for K/V reads
  const int pbase = w << 11;               // per-wave Pl base (2048 elems)

  const int srow = t >> 3;                 // staging row 0..31
  const int sc8 = (t & 7) * 8;             // staging chunk offset (elems)
  const int swz = (((t & 7) ^ (srow & 7)) << 3);   // swizzled LDS elem offset

  for (int it = 0; it < 32; ++it) {
    const int s0 = it * 64;
    // ---- issue staging loads before the barrier (regs are private) ----
    bf16x8 kreg[2], vreg[2];
#pragma unroll
    for (int i = 0; i < 2; ++i) {
      const int row = i * 32 + srow;
      kreg[i] = *(const bf16x8*)&Kp[kbase + (size_t)(s0 + row) * 512 + sc8];
      vreg[i] = *(const bf16x8*)&Vt[vbase + (size_t)row * 2048 + s0 + sc8];
    }
    __syncthreads();   // previous iteration's consumers done
#pragma unroll
    for (int i = 0; i < 2; ++i) {
      const int row = i * 32 + srow;
      *(bf16x8*)&Kl[(row << 6) + swz] = kreg[i];
      *(bf16x8*)&Vl[(row << 6) + swz] = vreg[i];
    }
    __syncthreads();   // staged tiles visible

    // ---- S^T = K Q^T : C-layout rows=keys(kt*16+quad*4+r), cols=q(nt*16+l15)
    f32x4 sacc[4][2] = {};
#pragma unroll
    for (int kc = 0; kc < 2; ++kc) {
#pragma unroll
      for (int kt = 0; kt < 4; ++kt) {
        bf16x8 kf = *(const bf16x8*)&Kl[((kt * 16 + l15) << 6) + (((kc * 4 + quad) ^ xk) << 3)];
#pragma unroll
        for (int nt = 0; nt < 2; ++nt)
          sacc[kt][nt] = __builtin_amdgcn_mfma_f32_16x16x32_bf16(kf, qf[nt][kc], sacc[kt][nt], 0, 0, 0);
      }
    }

    // ---- p = exp2(z); packed b64 P write (swizzled); per-lane li partials ----
#pragma unroll
    for (int nt = 0; nt < 2; ++nt) {
#pragma unroll
      for (int kt = 0; kt < 4; ++kt) {
        const float p0 = fast_exp2(sacc[kt][nt][0]);
        const float p1 = fast_exp2(sacc[kt][nt][1]);
        const float p2 = fast_exp2(sacc[kt][nt][2]);
        const float p3 = fast_exp2(sacc[kt][nt][3]);
        rs[nt] += (p0 + p1) + (p2 + p3);
        bf16x4v o;
        o.x = (bf16_t)p0; o.y = (bf16_t)p1; o.z = (bf16_t)p2; o.w = (bf16_t)p3;
        *(bf16x4v*)&Pl[pbase + ((nt * 16 + l15) << 6) + (((kt * 4 + quad) ^ xp) << 2)] = o;
      }
    }
    // no barrier: Pl region is wave-private, same-wave DS ops are in order

    // ---- O += P V : A-frag from Pl[q][s], B-frag from Vl[d][s] ----
#pragma unroll
    for (int kc = 0; kc < 2; ++kc) {
      bf16x8 pf[2];
#pragma unroll
      for (int mt = 0; mt < 2; ++mt)
        pf[mt] = *(const bf16x8*)&Pl[pbase + ((mt * 16 + l15) << 6) + (((kc * 8 + quad * 2) ^ xp) << 2)];
#pragma unroll
      for (int db = 0; db < 4; ++db) {
        bf16x8 vf = *(const bf16x8*)&Vl[((db * 16 + l15) << 6) + (((kc * 4 + quad) ^ xk) << 3)];
#pragma unroll
        for (int mt = 0; mt < 2; ++mt)
          oacc[mt][db] = __builtin_amdgcn_mfma_f32_16x16x32_bf16(pf[mt], vf, oacc[mt][db], 0, 0, 0);
      }
    }
  }

  // ---- finalize li: reduce across quads, deliver to O's C-layout ----
  float linv[2][4];
#pragma unroll
  for (int nt = 0; nt < 2; ++nt) {
    float rl = rs[nt];
    rl += __shfl_xor(rl, 16);
    rl += __shfl_xor(rl, 32);       // every lane with l15=x now has li(q=nt*16+x)
#pragma unroll
    for (int r = 0; r < 4; ++r)
      linv[nt][r] = 1.0f / __shfl(rl, quad * 4 + r);
  }

  // ---- epilogue: O * (1/l), store (B,T,32,64) ----
#pragma unroll
  for (int mt = 0; mt < 2; ++mt)
#pragma unroll
    for (int db = 0; db < 4; ++db)
#pragma unroll
      for (int r = 0; r < 4; ++r) {
        const int tt = t0 + mt * 16 + quad * 4 + r;
        const int d = db * 16 + l15;
        O[((size_t)(b * 2048 + tt) * 32 + h) * 64 + d] = (bf16_t)(oacc[mt][db][r] * linv[mt][r]);
      }
}

// ===================== launch =====================
extern "C" void kernel_launch(void* const* d_in, const int* in_sizes, int n_in,
                              void* d_out, int out_size, void* d_ws, size_t ws_size,
                              hipStream_t stream) {
  const float* q  = (const float*)d_in[0];
  const float* k  = (const float*)d_in[1];
  const float* v  = (const float*)d_in[2];
  const float* Wq = (const float*)d_in[3];
  const float* Wk = (const float*)d_in[4];
  const float* Wv = (const float*)d_in[5];
  const float* Wp = (const float*)d_in[6];
  const float* bp = (const float*)d_in[7];
  float* out = (float*)d_out;

  // workspace layout (bf16 elements); Ob aliases qb (q dead after Q-proj)
  bf16_t* ws = (bf16_t*)d_ws;
  bf16_t* qb  = ws;              // 8,388,608  (also Ob later)
  bf16_t* kb  = ws +  8388608;   // 8,388,608
  bf16_t* vb  = ws + 16777216;   // 8,388,608
  bf16_t* Wqb = ws + 25165824;   // 4,194,304
  bf16_t* Wkb = ws + 29360128;   // 1,048,576
  bf16_t* Wvb = ws + 30408704;   // 1,048,576
  bf16_t* Wpb = ws + 31457280;   // 4,194,304
  bf16_t* Qp  = ws + 35651584;   // 8,388,608  (B,T,32,64), pre-scaled by CSL
  bf16_t* Kp  = ws + 44040192;   // 2,097,152  (B,T,8,64)
  bf16_t* Vt  = ws + 46137344;   // 2,097,152  (B,8*64,T)
  bf16_t* Ob  = qb;              // reuse

  // fp32 -> bf16 conversions (2 fused launches)
  cvt3<<<dim3(8192, 3), 256, 0, stream>>>(q, k, v, qb, kb, vb, 8388608);
  cvt4<<<dim3(4096, 4), 256, 0, stream>>>(Wq, Wp, Wk, Wv, Wqb, Wpb, Wkb, Wvb,
                                          4194304, 1048576);

  // merged Q/K/V projections: one 768-block launch (3 blocks/CU)
  gemm_qkv<<<768, 256, 0, stream>>>(qb, Wqb, Qp, kb, Wkb, Kp, vb, Wvb, Vt);
  // flash attention
  attn_kernel<<<dim3(16, 32, 2), 256, 0, stream>>>(Qp, Kp, Vt, Ob);
  // output projection + bias (fp32 out)
  gemm_bias_f32<<<dim3(16, 32), 256, 0, stream>>>(Ob, Wpb, bp, out, 2048, 2048);
}